// Round 11
// baseline (425.687 us; speedup 1.0000x reference)
//
#include <hip/hip_runtime.h>
#include <hip/hip_bf16.h>

// ---------------------------------------------------------------------------
// Task1_bf_final_CSW2D round 11: one row per wave (4x wave count).
// R10 post-mortem: conv1 unchanged by load reduction -> not L1-bound.
// Both pipes <35% with ~10us of work each per CU in a 45us kernel =>
// latency-bound, insufficient resident waves (true VGPR incl. fragments
// caps residency ~3 waves/SIMD).  Fix: drop grid-stride, 1 row/wave,
// 8192 blocks for conv1/conv23 -> 4x block queue depth per CU.
// Everything else identical to R10.
// ---------------------------------------------------------------------------

#define E_    128
#define NPIX  32768
#define NS_   (NPIX * E_)
#define NSAMP 2048

static constexpr double PI_D     = 3.14159265358979323846;
static constexpr double FS_D     = 20832000.0;
static constexpr double FDEMOD_D = 5208000.0;
static constexpr double C_D      = 1540.0;

typedef __attribute__((ext_vector_type(8))) short short8;
typedef __attribute__((ext_vector_type(4))) float f32x4;

union U8 { uint4 u4; unsigned u32[4]; unsigned short us[8]; short8 s8; };

__device__ __forceinline__ unsigned short f2bf(float f) {
  unsigned u = __float_as_uint(f);
  unsigned r = (u + 0x7fffu + ((u >> 16) & 1u)) >> 16;
  return (unsigned short)r;
}
__device__ __forceinline__ float bflo(unsigned w) { return __uint_as_float(w << 16); }
__device__ __forceinline__ float bfhi(unsigned w) { return __uint_as_float(w & 0xFFFF0000u); }
__device__ __forceinline__ float bf2f(unsigned short s) {
  return __uint_as_float((unsigned)s << 16);
}

__device__ __forceinline__ float wave_reduce_sum(float v) {
  #pragma unroll
  for (int off = 32; off; off >>= 1) v += __shfl_xor(v, off);
  return v;
}
__device__ __forceinline__ float wave_reduce_max(float v) {
  #pragma unroll
  for (int off = 32; off; off >>= 1) v = fmaxf(v, __shfl_xor(v, off));
  return v;
}

// BN+relu one 16B unit (8 channels of one e), repack to bf16
__device__ __forceinline__ uint4 bn_unit(uint4 v, const float* A, const float* B) {
  U8 in; in.u4 = v;
  U8 out;
  #pragma unroll
  for (int w = 0; w < 4; ++w) {
    const unsigned wd = in.u32[w];
    const float yl = fmaxf(0.f, fmaf(A[2 * w], bflo(wd), B[2 * w]));
    const float yh = fmaxf(0.f, fmaf(A[2 * w + 1], bfhi(wd), B[2 * w + 1]));
    out.us[2 * w] = f2bf(yl);
    out.us[2 * w + 1] = f2bf(yh);
  }
  return out.u4;
}

// ---------------------------------------------------------------------------
// init: zero x0p halos + PER-BLOCK max of i^2+q^2 (float4, no atomics)
// ---------------------------------------------------------------------------
__global__ __launch_bounds__(256) void k_init(uint4* __restrict__ x0p,
                                              const float4* __restrict__ id4,
                                              const float4* __restrict__ qd4,
                                              float* __restrict__ pmaxsq) {
  const int idx = blockIdx.x * 256 + threadIdx.x;
  const int row = idx >> 5, k = idx & 31;
  if (k < 20) {
    const int q = (k < 8) ? k : (40 + (k - 8));   // uint4 0..7 and 40..51
    x0p[(size_t)row * 52 + q] = make_uint4(0, 0, 0, 0);
  }
  const float4 iv = id4[idx];
  const float4 qv = qd4[idx];
  float m = fmaxf(fmaxf(iv.x * iv.x + qv.x * qv.x, iv.y * iv.y + qv.y * qv.y),
                  fmaxf(iv.z * iv.z + qv.z * qv.z, iv.w * iv.w + qv.w * qv.w));
  m = wave_reduce_max(m);
  __shared__ float sm[4];
  if ((threadIdx.x & 63) == 0) sm[threadIdx.x >> 6] = m;
  __syncthreads();
  if (threadIdx.x == 0)
    pmaxsq[blockIdx.x] = fmaxf(fmaxf(sm[0], sm[1]), fmaxf(sm[2], sm[3]));
}

// ---------------------------------------------------------------------------
// beamform, e-major: block = (element e, 1024-pixel chunk).  Signal staged
// into LDS as (I,Q) float2; each tap gather = one ds_read_b64.  Each block
// self-reduces pmsq[4096] (L2/L3-hot) -> no separate nrmred launch.
// ---------------------------------------------------------------------------
__global__ __launch_bounds__(256) void k_beamform(
    const float4* __restrict__ id4, const float4* __restrict__ qd4,
    const float* __restrict__ angles, const float* __restrict__ ele_pos,
    const float* __restrict__ time_zero, const float* __restrict__ grid,
    const float* __restrict__ pmaxsq, unsigned* __restrict__ x0p) {
  __shared__ float2 sig[NSAMP];          // 16 KB
  __shared__ float smax[4];
  const int e = blockIdx.x & 127;
  const int chunk = blockIdx.x >> 7;     // 0..31

  const float4* irow = id4 + e * (NSAMP / 4);
  const float4* qrow = qd4 + e * (NSAMP / 4);
  #pragma unroll
  for (int k0 = 0; k0 < 2; ++k0) {
    const int k = k0 * 256 + threadIdx.x;
    const float4 iv = irow[k];
    const float4 qv = qrow[k];
    sig[4 * k + 0] = make_float2(iv.x, qv.x);
    sig[4 * k + 1] = make_float2(iv.y, qv.y);
    sig[4 * k + 2] = make_float2(iv.z, qv.z);
    sig[4 * k + 3] = make_float2(iv.w, qv.w);
  }
  // self-reduce the normalization max (16 KB, cached)
  float mx = 0.f;
  for (int i = threadIdx.x; i < 4096; i += 256) mx = fmaxf(mx, pmaxsq[i]);
  mx = wave_reduce_max(mx);
  if ((threadIdx.x & 63) == 0) smax[threadIdx.x >> 6] = mx;
  __syncthreads();
  const float inv =
      1.0f / sqrtf(fmaxf(fmaxf(smax[0], smax[1]), fmaxf(smax[2], smax[3])));

  const float ang = angles[0];
  const float tz  = time_zero[0];

  constexpr float SC    = (float)(FS_D / C_D);
  constexpr float TH2R  = (float)(2.0 * FDEMOD_D / C_D);
  constexpr float TWOPI = (float)(2.0 * PI_D);

  const float sa = __sinf(ang);
  const float ca = __cosf(ang);
  const float ta = sa / ca;
  const float ex  = ele_pos[e * 3];
  const float ex0 = ele_pos[0];
  const float exl = ele_pos[127 * 3];

  #pragma unroll
  for (int s = 0; s < 4; ++s) {
    const int p = chunk * 1024 + s * 256 + threadIdx.x;
    const float px = grid[p * 3 + 0];
    const float pz = grid[p * 3 + 2];

    const float txdel = (px * sa + pz * ca + tz * (float)C_D) * SC;
    const float dx = px - ex;
    const float rxdel = sqrtf(dx * dx + pz * pz) * SC;

    const float delays = txdel + rxdel;
    const float d0 = floorf(delays);
    const float frac = delays - d0;
    const int i0 = (int)d0;

    const int c0 = min(max(i0, 0), NSAMP - 1);
    const int c1 = min(max(i0 + 1, 0), NSAMP - 1);
    const float2 s0 = sig[c0];
    const float2 s1 = sig[c1];
    const bool m0 = (i0 >= 0) && (i0 < NSAMP);
    const bool m1 = (i0 + 1 >= 0) && (i0 + 1 < NSAMP);
    const float iv0 = m0 ? s0.x : 0.f;
    const float qv0 = m0 ? s0.y : 0.f;
    const float iv1 = m1 ? s1.x : 0.f;
    const float qv1 = m1 ? s1.y : 0.f;
    const float ifoc = (iv0 * (1.f - frac) + iv1 * frac) * inv;
    const float qfoc = (qv0 * (1.f - frac) + qv1 * frac) * inv;

    // theta/2pi = delays*0.25 - pz*TH2R  (exact: FS = 4*FDEMOD)
    const float trev = fmaf(delays, 0.25f, -pz * TH2R);
    const float fr = trev - floorf(trev);
    const float st = __sinf(fr * TWOPI);
    const float ct = __cosf(fr * TWOPI);
    const float ir = ifoc * ct - qfoc * st;
    const float qr = qfoc * ct + ifoc * st;

    const float avx = fabsf(dx);
    const bool mrx = (fabsf(pz) > avx) || (avx <= 0.001f) ||
                     ((dx >= 0.001f) && (px <= ex0)) ||
                     ((dx <= -0.001f) && (px >= exl));
    const float xproj = px - pz * ta;
    const bool mtx = (xproj >= ex0 * 1.2f) && (xproj <= exl * 1.2f);
    const float a = (mrx && mtx) ? 1.f : 0.f;

    x0p[(size_t)p * 208 + 32 + e] =
        (unsigned)f2bf(ir * a) | ((unsigned)f2bf(qr * a) << 16);
  }
}

// ---------------------------------------------------------------------------
// conv1: IC=2, K=65, pad=32, OC=8.  MFMA, taps padded to 80 (5 mfma / tile).
// ONE ROW PER WAVE (32768 waves, 8192 blocks).  Rolling-window fragments:
// 12 loads/row.  Also emits per-row e-sums (folded k_esum).
// Output: compact [p][128][8ch] (16B per e).
// ---------------------------------------------------------------------------
__global__ __launch_bounds__(256) void k_conv1(
    const unsigned* __restrict__ x0p, const float* __restrict__ wgt,
    const float* __restrict__ bias, uint2* __restrict__ outp,
    float* __restrict__ partial,
    float* __restrict__ sumI, float* __restrict__ sumQ) {
  const int tid = threadIdx.x;
  const int lane = tid & 63;
  const int wv = tid >> 6;
  const int p = blockIdx.x * 4 + wv;          // one row per wave
  const int n = lane & 15, kq = lane >> 4;

  short8 af[5];
  #pragma unroll
  for (int m = 0; m < 5; ++m) {
    U8 u;
    #pragma unroll
    for (int j = 0; j < 8; ++j) {
      const int tap = m * 16 + kq * 4 + (j >> 1);
      const int i = j & 1;
      const float w = (n < 8 && tap < 65) ? wgt[(n * 2 + i) * 65 + tap] : 0.f;
      u.us[j] = f2bf(w);
    }
    af[m] = u.s8;
  }
  float bias_r[4];
  #pragma unroll
  for (int r = 0; r < 4; ++r) {
    const int oo = kq * 4 + r;
    bias_r[r] = (oo < 8) ? bias[oo] : 0.f;
  }

  float sum[4] = {0, 0, 0, 0}, ssq[4] = {0, 0, 0, 0};

  {
    const unsigned* row = x0p + (size_t)p * 208;
    uint2* orow = outp + (size_t)p * 256;
    const int sbase = n + kq * 4;

    // e-sums for k_final (folded k_esum; bf16 inputs)
    {
      const unsigned v0 = row[32 + lane];
      const unsigned v1 = row[96 + lane];
      float si = bflo(v0) + bflo(v1);
      float sq = bfhi(v0) + bfhi(v1);
      si = wave_reduce_sum(si);
      sq = wave_reduce_sum(sq);
      if (lane == 0) { sumI[p] = si; sumQ[p] = sq; }
    }

    U8 f[5];
    #pragma unroll
    for (int j = 0; j < 5; ++j)
      f[j].u4 = *(const uint4*)(row + sbase + 16 * j);

    #pragma unroll
    for (int t = 0; t < 8; ++t) {
      f32x4 acc = {bias_r[0], bias_r[1], bias_r[2], bias_r[3]};
      #pragma unroll
      for (int m = 0; m < 5; ++m)
        acc = __builtin_amdgcn_mfma_f32_16x16x32_bf16(af[m], f[m].s8, acc, 0, 0, 0);

      if (lane < 32) {
        const unsigned lo = (unsigned)f2bf(acc[0]) | ((unsigned)f2bf(acc[1]) << 16);
        const unsigned hi = (unsigned)f2bf(acc[2]) | ((unsigned)f2bf(acc[3]) << 16);
        orow[(t * 16 + n) * 2 + kq] = make_uint2(lo, hi);
        #pragma unroll
        for (int r = 0; r < 4; ++r) { const float v = acc[r]; sum[r] += v; ssq[r] += v * v; }
      }
      if (t < 7) {
        #pragma unroll
        for (int j = 0; j < 4; ++j) f[j] = f[j + 1];
        f[4].u4 = *(const uint4*)(row + sbase + 16 * (t + 5));
      }
    }
  }

  #pragma unroll
  for (int off = 1; off <= 8; off <<= 1)
    #pragma unroll
    for (int r = 0; r < 4; ++r) { sum[r] += __shfl_xor(sum[r], off); ssq[r] += __shfl_xor(ssq[r], off); }
  __shared__ float s_red[4][16];
  if (lane == 0)
    #pragma unroll
    for (int r = 0; r < 4; ++r) { s_red[wv][r] = sum[r]; s_red[wv][8 + r] = ssq[r]; }
  if (lane == 16)
    #pragma unroll
    for (int r = 0; r < 4; ++r) { s_red[wv][4 + r] = sum[r]; s_red[wv][12 + r] = ssq[r]; }
  __syncthreads();
  if (tid < 16)
    partial[blockIdx.x * 16 + tid] =
        s_red[0][tid] + s_red[1][tid] + s_red[2][tid] + s_red[3][tid];
}

// ---------------------------------------------------------------------------
// conv2/3: IC=8, K=15, pad=7, OC=8.  ONE ROW PER WAVE (8192 blocks).
// Per-wave PRIVATE LDS row staging (no intra-loop barriers).  BN+relu once
// per element; halos zeroed (pad AFTER BN+relu).  Fragments: ds_read_b128.
// ---------------------------------------------------------------------------
__global__ __launch_bounds__(256) void k_conv23(
    const uint4* __restrict__ inp, const float* __restrict__ wgt,
    const float* __restrict__ bias, const float* __restrict__ bnAB,
    uint2* __restrict__ outp, float* __restrict__ partial) {
  __shared__ uint4 s_row[4][144];
  const int tid = threadIdx.x;
  const int lane = tid & 63;
  const int wv = tid >> 6;
  const int p = blockIdx.x * 4 + wv;          // one row per wave
  const int n = lane & 15, kq = lane >> 4;

  float A[8], Bc[8];
  #pragma unroll
  for (int i = 0; i < 8; ++i) { A[i] = bnAB[2 * i]; Bc[i] = bnAB[2 * i + 1]; }

  short8 af[4];
  #pragma unroll
  for (int m = 0; m < 4; ++m) {
    U8 u;
    #pragma unroll
    for (int j = 0; j < 8; ++j) {
      const int tap = m * 4 + kq;
      const float w = (n < 8 && tap < 15) ? wgt[(n * 8 + j) * 15 + tap] : 0.f;
      u.us[j] = f2bf(w);
    }
    af[m] = u.s8;
  }
  float bias_r[4];
  #pragma unroll
  for (int r = 0; r < 4; ++r) {
    const int oo = kq * 4 + r;
    bias_r[r] = (oo < 8) ? bias[oo] : 0.f;
  }

  uint4* lds = s_row[wv];
  if (lane < 7)  lds[lane] = make_uint4(0, 0, 0, 0);
  if (lane >= 7 && lane < 16) lds[128 + lane] = make_uint4(0, 0, 0, 0);

  float sum[4] = {0, 0, 0, 0}, ssq[4] = {0, 0, 0, 0};

  {
    const uint4* grow = inp + (size_t)p * 128;
    const uint4 v0 = grow[lane];
    const uint4 v1 = grow[64 + lane];
    lds[7 + lane]  = bn_unit(v0, A, Bc);
    lds[71 + lane] = bn_unit(v1, A, Bc);

    uint2* orow = outp + (size_t)p * 256;
    #pragma unroll
    for (int t = 0; t < 8; ++t) {
      f32x4 acc = {bias_r[0], bias_r[1], bias_r[2], bias_r[3]};
      const int base = t * 16 + n + kq;
      #pragma unroll
      for (int m = 0; m < 4; ++m) {
        U8 b;
        b.u4 = lds[base + m * 4];
        acc = __builtin_amdgcn_mfma_f32_16x16x32_bf16(af[m], b.s8, acc, 0, 0, 0);
      }
      if (lane < 32) {
        const unsigned lo = (unsigned)f2bf(acc[0]) | ((unsigned)f2bf(acc[1]) << 16);
        const unsigned hi = (unsigned)f2bf(acc[2]) | ((unsigned)f2bf(acc[3]) << 16);
        orow[(t * 16 + n) * 2 + kq] = make_uint2(lo, hi);
        #pragma unroll
        for (int r = 0; r < 4; ++r) { const float v = acc[r]; sum[r] += v; ssq[r] += v * v; }
      }
    }
  }

  #pragma unroll
  for (int off = 1; off <= 8; off <<= 1)
    #pragma unroll
    for (int r = 0; r < 4; ++r) { sum[r] += __shfl_xor(sum[r], off); ssq[r] += __shfl_xor(ssq[r], off); }
  __shared__ float s_red[4][16];
  if (lane == 0)
    #pragma unroll
    for (int r = 0; r < 4; ++r) { s_red[wv][r] = sum[r]; s_red[wv][8 + r] = ssq[r]; }
  if (lane == 16)
    #pragma unroll
    for (int r = 0; r < 4; ++r) { s_red[wv][4 + r] = sum[r]; s_red[wv][12 + r] = ssq[r]; }
  __syncthreads();
  if (tid < 16)
    partial[blockIdx.x * 16 + tid] =
        s_red[0][tid] + s_red[1][tid] + s_red[2][tid] + s_red[3][tid];
}

// ---------------------------------------------------------------------------
// conv4: IC=8, K=3, pad=1, OC=1.  VALU; BN3+relu fused on load; pad taps
// contribute exactly 0.  Output bf16 (ushort).
// ---------------------------------------------------------------------------
__global__ __launch_bounds__(256) void k_conv4(
    const uint4* __restrict__ inp, const float* __restrict__ bnAB,
    const float* __restrict__ w4, const float* __restrict__ b4,
    unsigned short* __restrict__ y4b, float* __restrict__ partial) {
  const int idx = blockIdx.x * 256 + threadIdx.x;
  const int p = idx >> 7, e = idx & 127;

  float A[8], Bc[8];
  #pragma unroll
  for (int i = 0; i < 8; ++i) { A[i] = bnAB[2 * i]; Bc[i] = bnAB[2 * i + 1]; }

  float acc = b4[0];
  const uint4* row = inp + (size_t)p * 128 + e;
  #pragma unroll
  for (int kt = 0; kt < 3; ++kt) {
    const int ee = e + kt - 1;
    if (ee >= 0 && ee < E_) {
      U8 u; u.u4 = row[kt - 1];
      #pragma unroll
      for (int i = 0; i < 8; ++i) {
        const unsigned wd = u.u32[i >> 1];
        const float x = (i & 1) ? bfhi(wd) : bflo(wd);
        const float v = fmaxf(0.f, fmaf(A[i], x, Bc[i]));
        acc = fmaf(w4[i * 3 + kt], v, acc);
      }
    }
  }
  y4b[idx] = f2bf(acc);

  float s = wave_reduce_sum(acc);
  float ss = wave_reduce_sum(acc * acc);
  __shared__ float sm[4][2];
  if ((threadIdx.x & 63) == 0) { sm[threadIdx.x >> 6][0] = s; sm[threadIdx.x >> 6][1] = ss; }
  __syncthreads();
  if (threadIdx.x == 0) {
    partial[blockIdx.x * 2 + 0] = sm[0][0] + sm[1][0] + sm[2][0] + sm[3][0];
    partial[blockIdx.x * 2 + 1] = sm[0][1] + sm[1][1] + sm[2][1] + sm[3][1];
  }
}

// ---------------------------------------------------------------------------
// BN stats finalize: A = g*rsqrt(var+eps), B = beta - mu*A
// ---------------------------------------------------------------------------
__global__ __launch_bounds__(256) void k_stats(const float* __restrict__ partial,
                                               int nblk, int oc,
                                               const float* __restrict__ g,
                                               const float* __restrict__ beta,
                                               float* __restrict__ ssout) {
  const int o = blockIdx.x;
  float s = 0.f, ss = 0.f;
  for (int b = threadIdx.x; b < nblk; b += 256) {
    s  += partial[b * 2 * oc + o];
    ss += partial[b * 2 * oc + oc + o];
  }
  s = wave_reduce_sum(s);
  ss = wave_reduce_sum(ss);
  __shared__ float sm[4][2];
  if ((threadIdx.x & 63) == 0) { sm[threadIdx.x >> 6][0] = s; sm[threadIdx.x >> 6][1] = ss; }
  __syncthreads();
  if (threadIdx.x == 0) {
    s  = sm[0][0] + sm[1][0] + sm[2][0] + sm[3][0];
    ss = sm[0][1] + sm[1][1] + sm[2][1] + sm[3][1];
    const float count = (float)NS_;
    const float mu = s / count;
    const float var = fmaxf(ss / count - mu * mu, 0.f);
    const float Av = g[o] * rsqrtf(var + 1e-5f);
    ssout[2 * o] = Av;
    ssout[2 * o + 1] = beta[o] - mu * Av;
  }
}

// ---------------------------------------------------------------------------
// final: singleW = sum_e relu(A4*y4+B4); comp = singleW*(sum_e x)/E; dB.
// Per-block max -> pmax[] (no same-address atomics).
// ---------------------------------------------------------------------------
__global__ __launch_bounds__(256) void k_final(const float* __restrict__ sumI,
                                               const float* __restrict__ sumQ,
                                               const unsigned short* __restrict__ y4b,
                                               const float* __restrict__ ss4,
                                               float* __restrict__ ydb,
                                               float* __restrict__ pmax) {
  const int w = threadIdx.x >> 6;
  const int lane = threadIdx.x & 63;
  const int p = blockIdx.x * 4 + w;
  const float A = ss4[0], B = ss4[1];
  const size_t base = (size_t)p * E_;

  float sw = fmaxf(0.f, fmaf(A, bf2f(y4b[base + lane]), B)) +
             fmaxf(0.f, fmaf(A, bf2f(y4b[base + lane + 64]), B));
  sw = wave_reduce_sum(sw);

  __shared__ float s_m[4];
  if (lane == 0) {
    const float ci = sw * sumI[p] * (1.f / (float)E_);
    const float cq = sw * sumQ[p] * (1.f / (float)E_);
    const float mag = sqrtf(ci * ci + cq * cq);
    const float v = 20.f * log10f(mag + 1e-20f);
    ydb[p] = v;
    s_m[w] = v;
  }
  __syncthreads();
  if (threadIdx.x == 0)
    pmax[blockIdx.x] = fmaxf(fmaxf(s_m[0], s_m[1]), fmaxf(s_m[2], s_m[3]));
}

// k_sub with inline global-max: each block re-reduces pmax[8192]
__global__ __launch_bounds__(256) void k_sub(const float* __restrict__ ydb,
                                             const float* __restrict__ pmax,
                                             float* __restrict__ out) {
  float m = -3.4e38f;
  for (int i = threadIdx.x; i < NPIX / 4; i += 256) m = fmaxf(m, pmax[i]);
  m = wave_reduce_max(m);
  __shared__ float sm[4];
  if ((threadIdx.x & 63) == 0) sm[threadIdx.x >> 6] = m;
  __syncthreads();
  __shared__ float sgm;
  if (threadIdx.x == 0)
    sgm = fmaxf(fmaxf(sm[0], sm[1]), fmaxf(sm[2], sm[3]));
  __syncthreads();
  const int i = blockIdx.x * 256 + threadIdx.x;
  out[i] = ydb[i] - sgm;
}

// ---------------------------------------------------------------------------
// Workspace layout (bytes).  Region A is time-multiplexed:
//   x0p (27MB) -> buf2 (67MB, dead after conv3) -> y4b (8.4MB) + ydb + pmax.
// ---------------------------------------------------------------------------
static constexpr size_t OFF_A     = 0;            // 67,108,864 region
static constexpr size_t OFF_Y4    = 0;            // bf16 [NS]  (in A)
static constexpr size_t OFF_YDB   = 16777216;     // f32 [NPIX] (in A)
static constexpr size_t OFF_PMAX  = 16908288;     // f32 [8192] (in A)
static constexpr size_t OFF_BUF1  = 67108864;     // 67,108,864
static constexpr size_t OFF_SUMI  = 134217728;    // 131,072
static constexpr size_t OFF_SUMQ  = 134348800;    // 131,072
static constexpr size_t OFF_PART  = 134479872;    // 524,288 (8192 blk * 16 f32)
static constexpr size_t OFF_PMSQ  = 135004160;    // 16,384 (4096 f32)
static constexpr size_t OFF_SS    = 135020544;    // 256

extern "C" void kernel_launch(void* const* d_in, const int* in_sizes, int n_in,
                              void* d_out, int out_size, void* d_ws, size_t ws_size,
                              hipStream_t stream) {
  const float* idata     = (const float*)d_in[0];
  const float* qdata     = (const float*)d_in[1];
  const float* angles    = (const float*)d_in[2];
  const float* ele_pos   = (const float*)d_in[3];
  const float* time_zero = (const float*)d_in[4];
  const float* grid      = (const float*)d_in[5];
  const float* w1 = (const float*)d_in[6];  const float* b1 = (const float*)d_in[7];
  const float* g1 = (const float*)d_in[8];  const float* be1 = (const float*)d_in[9];
  const float* w2 = (const float*)d_in[10]; const float* b2 = (const float*)d_in[11];
  const float* g2 = (const float*)d_in[12]; const float* be2 = (const float*)d_in[13];
  const float* w3 = (const float*)d_in[14]; const float* b3 = (const float*)d_in[15];
  const float* g3 = (const float*)d_in[16]; const float* be3 = (const float*)d_in[17];
  const float* w4 = (const float*)d_in[18]; const float* b4 = (const float*)d_in[19];
  const float* g4 = (const float*)d_in[20]; const float* be4 = (const float*)d_in[21];

  char* ws = (char*)d_ws;
  unsigned*       x0p   = (unsigned*)(ws + OFF_A);       // [p][208] bf16-pairs
  uint4*          buf2  = (uint4*)(ws + OFF_A);          // [p][128] units
  unsigned short* y4b   = (unsigned short*)(ws + OFF_Y4);
  float*          ydb   = (float*)(ws + OFF_YDB);
  float*          pmax  = (float*)(ws + OFF_PMAX);
  uint4*          buf1  = (uint4*)(ws + OFF_BUF1);
  float*          sumI  = (float*)(ws + OFF_SUMI);
  float*          sumQ  = (float*)(ws + OFF_SUMQ);
  float*          part  = (float*)(ws + OFF_PART);
  float*          pmsq  = (float*)(ws + OFF_PMSQ);
  float*          ssAB  = (float*)(ws + OFF_SS);

  k_init<<<4096, 256, 0, stream>>>((uint4*)x0p, (const float4*)idata,
                                   (const float4*)qdata, pmsq);
  k_beamform<<<4096, 256, 0, stream>>>((const float4*)idata, (const float4*)qdata,
                                       angles, ele_pos, time_zero, grid,
                                       pmsq, x0p);

  k_conv1<<<8192, 256, 0, stream>>>(x0p, w1, b1, (uint2*)buf1, part, sumI, sumQ);
  k_stats<<<8, 256, 0, stream>>>(part, 8192, 8, g1, be1, ssAB + 0);

  k_conv23<<<8192, 256, 0, stream>>>(buf1, w2, b2, ssAB + 0, (uint2*)buf2, part);
  k_stats<<<8, 256, 0, stream>>>(part, 8192, 8, g2, be2, ssAB + 16);

  k_conv23<<<8192, 256, 0, stream>>>(buf2, w3, b3, ssAB + 16, (uint2*)buf1, part);
  k_stats<<<8, 256, 0, stream>>>(part, 8192, 8, g3, be3, ssAB + 32);

  k_conv4<<<NS_ / 256, 256, 0, stream>>>(buf1, ssAB + 32, w4, b4, y4b, part);
  k_stats<<<1, 256, 0, stream>>>(part, NS_ / 256, 1, g4, be4, ssAB + 48);

  k_final<<<NPIX / 4, 256, 0, stream>>>(sumI, sumQ, y4b, ssAB + 48, ydb, pmax);
  k_sub<<<NPIX / 256, 256, 0, stream>>>(ydb, pmax, (float*)d_out);
}